// Round 1
// baseline (210.235 us; speedup 1.0000x reference)
//
#include <hip/hip_runtime.h>

#define N_NODES 10000
#define N_PAIRS 1200000
#define DIM 128

__global__ __launch_bounds__(128, 8)
void daa_fused_kernel(const float* __restrict__ features,
                      const float* __restrict__ dist,
                      const int* __restrict__ pair_node,
                      const int* __restrict__ pair_i,
                      const int* __restrict__ pair_j,
                      const float* __restrict__ pair_cos,
                      const float* __restrict__ W,
                      const float* __restrict__ b,
                      float* __restrict__ out)
{
    const int n = blockIdx.x;
    const int d = threadIdx.x;

    // pair_node is sorted: binary-search [lo, hi) = range of pairs for node n.
    // Redundant per-thread search; addresses are wave-uniform -> broadcast loads.
    int lo, hi;
    {
        int l = 0, r = N_PAIRS;
        while (l < r) { int m = (l + r) >> 1; if (pair_node[m] < n) l = m + 1; else r = m; }
        lo = l;
        r = N_PAIRS;
        while (l < r) { int m = (l + r) >> 1; if (pair_node[m] < n + 1) l = m + 1; else r = m; }
        hi = l;
    }

    const size_t drow = (size_t)n * N_NODES;
    float acc = 0.0f;

    int p = lo;
    // 4-way unroll: 4 independent gather chains for latency hiding.
    for (; p + 4 <= hi; p += 4) {
        const int i0 = pair_i[p+0], j0 = pair_j[p+0];
        const int i1 = pair_i[p+1], j1 = pair_j[p+1];
        const int i2 = pair_i[p+2], j2 = pair_j[p+2];
        const int i3 = pair_i[p+3], j3 = pair_j[p+3];
        const float c0 = pair_cos[p+0], c1 = pair_cos[p+1];
        const float c2 = pair_cos[p+2], c3 = pair_cos[p+3];

        const float w0 = c0 * dist[drow + i0] * dist[drow + j0];
        const float w1 = c1 * dist[drow + i1] * dist[drow + j1];
        const float w2 = c2 * dist[drow + i2] * dist[drow + j2];
        const float w3 = c3 * dist[drow + i3] * dist[drow + j3];

        const float fi0 = features[(size_t)i0 * DIM + d], fj0 = features[(size_t)j0 * DIM + d];
        const float fi1 = features[(size_t)i1 * DIM + d], fj1 = features[(size_t)j1 * DIM + d];
        const float fi2 = features[(size_t)i2 * DIM + d], fj2 = features[(size_t)j2 * DIM + d];
        const float fi3 = features[(size_t)i3 * DIM + d], fj3 = features[(size_t)j3 * DIM + d];

        acc += (fi0 + fj0) * w0;
        acc += (fi1 + fj1) * w1;
        acc += (fi2 + fj2) * w2;
        acc += (fi3 + fj3) * w3;
    }
    for (; p < hi; ++p) {
        const int i = pair_i[p], j = pair_j[p];
        const float w = pair_cos[p] * dist[drow + i] * dist[drow + j];
        acc += (features[(size_t)i * DIM + d] + features[(size_t)j * DIM + d]) * w;
    }

    // Fused epilogue: out[n][:] = acc_vec @ W + b.
    // acc is distributed one element per thread -> broadcast via LDS.
    __shared__ float sAcc[DIM];
    sAcc[d] = acc;
    __syncthreads();

    float o = b[d];
    #pragma unroll 8
    for (int k = 0; k < DIM; ++k) {
        o += sAcc[k] * W[k * DIM + d];   // W[k][d]: coalesced across threads, L2-hot
    }
    out[(size_t)n * DIM + d] = o;
}

extern "C" void kernel_launch(void* const* d_in, const int* in_sizes, int n_in,
                              void* d_out, int out_size, void* d_ws, size_t ws_size,
                              hipStream_t stream) {
    const float* features  = (const float*)d_in[0];
    const float* dist      = (const float*)d_in[1];
    const int*   pair_node = (const int*)  d_in[2];
    const int*   pair_i    = (const int*)  d_in[3];
    const int*   pair_j    = (const int*)  d_in[4];
    const float* pair_cos  = (const float*)d_in[5];
    const float* W         = (const float*)d_in[6];
    const float* b         = (const float*)d_in[7];
    float* out = (float*)d_out;

    daa_fused_kernel<<<N_NODES, DIM, 0, stream>>>(
        features, dist, pair_node, pair_i, pair_j, pair_cos, W, b, out);
}

// Round 2
// 193.475 us; speedup vs baseline: 1.0866x; 1.0866x over previous
//
#include <hip/hip_runtime.h>

#define N_NODES 10000
#define N_PAIRS 1200000
#define DIM 128

__device__ inline float bf2f(unsigned short u) {
    union { unsigned int i; float f; } x; x.i = ((unsigned int)u) << 16; return x.f;
}
__device__ inline unsigned short f2bf(float f) {
    union { float f; unsigned int i; } x; x.f = f;
    unsigned int r = x.i + 0x7FFFu + ((x.i >> 16) & 1u);   // round-to-nearest-even
    return (unsigned short)(r >> 16);
}

// ---------- Kernel A: FW = F @ W, stored bf16. W staged fully in LDS. ----------
__global__ __launch_bounds__(256)
void fw_gemm_kernel(const float* __restrict__ F, const float* __restrict__ W,
                    unsigned short* __restrict__ FWb)
{
    __shared__ float sW[DIM * DIM];   // 64 KiB
    __shared__ float sF[2][DIM];

    for (int idx = threadIdx.x; idx < DIM * DIM; idx += 256)
        sW[idx] = W[idx];

    const int sub = threadIdx.x >> 7;   // 0..1 (which of 2 rows this pass)
    const int d   = threadIdx.x & 127;  // output dim
    const int row0 = blockIdx.x * 32;

    for (int rp = 0; rp < 16; ++rp) {
        const int m = row0 + rp * 2 + sub;
        __syncthreads();
        sF[sub][d] = (m < N_NODES) ? F[(size_t)m * DIM + d] : 0.0f;
        __syncthreads();
        float o = 0.0f;
        #pragma unroll 16
        for (int k = 0; k < DIM; ++k)
            o += sF[sub][k] * sW[k * DIM + d];   // 2-way bank alias: free
        if (m < N_NODES) FWb[(size_t)m * DIM + d] = f2bf(o);
    }
}

// ---------- Kernel B: per-pair weights. 1 thread = 1 pair, max MLP. ----------
__global__ __launch_bounds__(256)
void pair_w_kernel(const float* __restrict__ dist,
                   const int* __restrict__ pair_node,
                   const int* __restrict__ pair_i,
                   const int* __restrict__ pair_j,
                   const float* __restrict__ pair_cos,
                   float* __restrict__ wbuf)
{
    const int p = blockIdx.x * 256 + threadIdx.x;
    if (p >= N_PAIRS) return;
    const size_t row = (size_t)pair_node[p] * N_NODES;
    const float di = dist[row + pair_i[p]];
    const float dj = dist[row + pair_j[p]];
    wbuf[p] = pair_cos[p] * di * dj;
}

// ---------- Kernel C: segment-sum of w*(FW[i]+FW[j]) + b. ----------
// 512 threads = 8 pair-lanes (1 wave each) x 64 threads (2 dims each, ushort2).
__global__ __launch_bounds__(512, 4)
void seg_kernel(const ushort2* __restrict__ FWb2,   // [N_NODES][64]
                const float* __restrict__ wbuf,
                const int* __restrict__ pair_node,
                const int* __restrict__ pair_i,
                const int* __restrict__ pair_j,
                const float* __restrict__ b,
                float* __restrict__ out)
{
    const int n  = blockIdx.x;
    const int pl = threadIdx.x >> 6;   // 0..7 pair-lane (== wave id)
    const int d2 = threadIdx.x & 63;   // dim pair index

    // binary search [lo, hi) in sorted pair_node (wave-uniform addresses)
    int lo, hi;
    {
        int l = 0, r = N_PAIRS;
        while (l < r) { int m = (l + r) >> 1; if (pair_node[m] < n) l = m + 1; else r = m; }
        lo = l;
        r = N_PAIRS;
        while (l < r) { int m = (l + r) >> 1; if (pair_node[m] < n + 1) l = m + 1; else r = m; }
        hi = l;
    }

    float ax = 0.0f, ay = 0.0f;
    int p = lo + pl;
    // unroll 2: 4 row-gathers in flight per wave
    for (; p + 8 < hi; p += 16) {
        const int i0 = pair_i[p],     j0 = pair_j[p];
        const int i1 = pair_i[p + 8], j1 = pair_j[p + 8];
        const float w0 = wbuf[p], w1 = wbuf[p + 8];
        const ushort2 fi0 = FWb2[(size_t)i0 * 64 + d2];
        const ushort2 fj0 = FWb2[(size_t)j0 * 64 + d2];
        const ushort2 fi1 = FWb2[(size_t)i1 * 64 + d2];
        const ushort2 fj1 = FWb2[(size_t)j1 * 64 + d2];
        ax += w0 * (bf2f(fi0.x) + bf2f(fj0.x));
        ay += w0 * (bf2f(fi0.y) + bf2f(fj0.y));
        ax += w1 * (bf2f(fi1.x) + bf2f(fj1.x));
        ay += w1 * (bf2f(fi1.y) + bf2f(fj1.y));
    }
    if (p < hi) {
        const int i = pair_i[p], j = pair_j[p];
        const float w = wbuf[p];
        const ushort2 fi = FWb2[(size_t)i * 64 + d2];
        const ushort2 fj = FWb2[(size_t)j * 64 + d2];
        ax += w * (bf2f(fi.x) + bf2f(fj.x));
        ay += w * (bf2f(fi.y) + bf2f(fj.y));
    }

    __shared__ float sAcc[8][64][2];
    sAcc[pl][d2][0] = ax;
    sAcc[pl][d2][1] = ay;
    __syncthreads();

    if (pl == 0) {
        float tx = ax, ty = ay;
        #pragma unroll
        for (int q = 1; q < 8; ++q) { tx += sAcc[q][d2][0]; ty += sAcc[q][d2][1]; }
        const float2 bb = ((const float2*)b)[d2];
        float2 o; o.x = tx + bb.x; o.y = ty + bb.y;
        ((float2*)out)[(size_t)n * 64 + d2] = o;
    }
}

extern "C" void kernel_launch(void* const* d_in, const int* in_sizes, int n_in,
                              void* d_out, int out_size, void* d_ws, size_t ws_size,
                              hipStream_t stream) {
    const float* features  = (const float*)d_in[0];
    const float* dist      = (const float*)d_in[1];
    const int*   pair_node = (const int*)  d_in[2];
    const int*   pair_i    = (const int*)  d_in[3];
    const int*   pair_j    = (const int*)  d_in[4];
    const float* pair_cos  = (const float*)d_in[5];
    const float* W         = (const float*)d_in[6];
    const float* b         = (const float*)d_in[7];
    float* out = (float*)d_out;

    // workspace layout: w[N_PAIRS] f32 (4.8 MB), then FWb[N_NODES*DIM] bf16 (2.56 MB)
    float* wbuf = (float*)d_ws;
    unsigned short* FWb = (unsigned short*)((char*)d_ws + (size_t)N_PAIRS * sizeof(float));

    fw_gemm_kernel<<<(N_NODES + 31) / 32, 256, 0, stream>>>(features, W, FWb);
    pair_w_kernel<<<(N_PAIRS + 255) / 256, 256, 0, stream>>>(
        dist, pair_node, pair_i, pair_j, pair_cos, wbuf);
    seg_kernel<<<N_NODES, 512, 0, stream>>>(
        (const ushort2*)FWb, wbuf, pair_node, pair_i, pair_j, b, out);
}

// Round 3
// 172.777 us; speedup vs baseline: 1.2168x; 1.1198x over previous
//
#include <hip/hip_runtime.h>

#define N_NODES 10000
#define N_PAIRS 1200000
#define DIM 128
#define WCHUNK 256   // pairs staged in LDS per chunk (max node count ~165, so 1 pass)

__device__ inline float bf2f(unsigned short u) {
    union { unsigned int i; float f; } x; x.i = ((unsigned int)u) << 16; return x.f;
}
__device__ inline unsigned short f2bf(float f) {
    union { float f; unsigned int i; } x; x.f = f;
    unsigned int r = x.i + 0x7FFFu + ((x.i >> 16) & 1u);   // round-to-nearest-even
    return (unsigned short)(r >> 16);
}

// ---------- Kernel A: FW = F @ W, stored bf16. W staged fully in LDS. ----------
__global__ __launch_bounds__(256)
void fw_gemm_kernel(const float* __restrict__ F, const float* __restrict__ W,
                    unsigned short* __restrict__ FWb)
{
    __shared__ float sW[DIM * DIM];   // 64 KiB
    __shared__ float sF[2][DIM];

    for (int idx = threadIdx.x; idx < DIM * DIM; idx += 256)
        sW[idx] = W[idx];

    const int sub = threadIdx.x >> 7;   // 0..1
    const int d   = threadIdx.x & 127;
    const int row0 = blockIdx.x * 32;

    for (int rp = 0; rp < 16; ++rp) {
        const int m = row0 + rp * 2 + sub;
        __syncthreads();
        sF[sub][d] = (m < N_NODES) ? F[(size_t)m * DIM + d] : 0.0f;
        __syncthreads();
        float o = 0.0f;
        #pragma unroll 16
        for (int k = 0; k < DIM; ++k)
            o += sF[sub][k] * sW[k * DIM + d];
        if (m < N_NODES) FWb[(size_t)m * DIM + d] = f2bf(o);
    }
}

// ---------- Fused kernel: per-node pair weights (burst, row-local) + segment-sum ----------
// 512 threads = 8 waves. Phase 1: all threads compute w into LDS (dist row hot in L1/L2).
// Phase 2: 8 pair-lanes x 64 dim-threads accumulate w*(FW[i]+FW[j]) from L2-resident FW.
__global__ __launch_bounds__(512, 4)
void fused_seg_kernel(const float* __restrict__ dist,
                      const ushort2* __restrict__ FWb2,   // [N_NODES][64]
                      const int* __restrict__ pair_node,
                      const int* __restrict__ pair_i,
                      const int* __restrict__ pair_j,
                      const float* __restrict__ pair_cos,
                      const float* __restrict__ b,
                      float* __restrict__ out)
{
    const int n   = blockIdx.x;
    const int tid = threadIdx.x;
    const int pl  = tid >> 6;   // pair-lane (wave id) 0..7
    const int d2  = tid & 63;   // dim-pair index

    __shared__ float sw[WCHUNK];
    __shared__ int   si[WCHUNK];
    __shared__ int   sj[WCHUNK];
    __shared__ float sAcc[8][64][2];

    // binary search [lo, hi) in sorted pair_node (wave-uniform)
    int lo, hi;
    {
        int l = 0, r = N_PAIRS;
        while (l < r) { int m = (l + r) >> 1; if (pair_node[m] < n) l = m + 1; else r = m; }
        lo = l;
        r = N_PAIRS;
        while (l < r) { int m = (l + r) >> 1; if (pair_node[m] < n + 1) l = m + 1; else r = m; }
        hi = l;
    }

    const size_t drow = (size_t)n * N_NODES;
    float ax = 0.0f, ay = 0.0f;

    for (int base = lo; base < hi; base += WCHUNK) {
        const int m = min(WCHUNK, hi - base);

        // ---- phase 1: burst-compute pair weights into LDS ----
        for (int t = tid; t < m; t += 512) {
            const int i = pair_i[base + t];
            const int j = pair_j[base + t];
            si[t] = i;
            sj[t] = j;
            sw[t] = pair_cos[base + t] * dist[drow + i] * dist[drow + j];
        }
        __syncthreads();

        // ---- phase 2: accumulate w*(FW[i]+FW[j]), unroll 2 (4 row-gathers in flight) ----
        int q = pl;
        for (; q + 8 < m; q += 16) {
            const int i0 = si[q],     j0 = sj[q];
            const int i1 = si[q + 8], j1 = sj[q + 8];
            const float w0 = sw[q], w1 = sw[q + 8];
            const ushort2 fi0 = FWb2[(size_t)i0 * 64 + d2];
            const ushort2 fj0 = FWb2[(size_t)j0 * 64 + d2];
            const ushort2 fi1 = FWb2[(size_t)i1 * 64 + d2];
            const ushort2 fj1 = FWb2[(size_t)j1 * 64 + d2];
            ax += w0 * (bf2f(fi0.x) + bf2f(fj0.x));
            ay += w0 * (bf2f(fi0.y) + bf2f(fj0.y));
            ax += w1 * (bf2f(fi1.x) + bf2f(fj1.x));
            ay += w1 * (bf2f(fi1.y) + bf2f(fj1.y));
        }
        if (q < m) {
            const int i = si[q], j = sj[q];
            const float w = sw[q];
            const ushort2 fi = FWb2[(size_t)i * 64 + d2];
            const ushort2 fj = FWb2[(size_t)j * 64 + d2];
            ax += w * (bf2f(fi.x) + bf2f(fj.x));
            ay += w * (bf2f(fi.y) + bf2f(fj.y));
        }
        __syncthreads();   // LDS reused next chunk
    }

    sAcc[pl][d2][0] = ax;
    sAcc[pl][d2][1] = ay;
    __syncthreads();

    if (pl == 0) {
        float tx = ax, ty = ay;
        #pragma unroll
        for (int q = 1; q < 8; ++q) { tx += sAcc[q][d2][0]; ty += sAcc[q][d2][1]; }
        const float2 bb = ((const float2*)b)[d2];
        float2 o; o.x = tx + bb.x; o.y = ty + bb.y;
        ((float2*)out)[(size_t)n * 64 + d2] = o;
    }
}

extern "C" void kernel_launch(void* const* d_in, const int* in_sizes, int n_in,
                              void* d_out, int out_size, void* d_ws, size_t ws_size,
                              hipStream_t stream) {
    const float* features  = (const float*)d_in[0];
    const float* dist      = (const float*)d_in[1];
    const int*   pair_node = (const int*)  d_in[2];
    const int*   pair_i    = (const int*)  d_in[3];
    const int*   pair_j    = (const int*)  d_in[4];
    const float* pair_cos  = (const float*)d_in[5];
    const float* W         = (const float*)d_in[6];
    const float* b         = (const float*)d_in[7];
    float* out = (float*)d_out;

    // workspace: FWb[N_NODES*DIM] bf16 (2.56 MB)
    unsigned short* FWb = (unsigned short*)d_ws;

    fw_gemm_kernel<<<(N_NODES + 31) / 32, 256, 0, stream>>>(features, W, FWb);
    fused_seg_kernel<<<N_NODES, 512, 0, stream>>>(
        dist, (const ushort2*)FWb, pair_node, pair_i, pair_j, pair_cos, b, out);
}

// Round 4
// 111.889 us; speedup vs baseline: 1.8790x; 1.5442x over previous
//
#include <hip/hip_runtime.h>

#define N_NODES 10000
#define N_PAIRS 1200000
#define DIM 128
#define WCHUNK 256   // pairs per LDS chunk; node counts ~120±11, so always 1 pass

__device__ inline float bf2f(unsigned short u) {
    union { unsigned int i; float f; } x; x.i = ((unsigned int)u) << 16; return x.f;
}
__device__ inline unsigned short f2bf(float f) {
    union { float f; unsigned int i; } x; x.f = f;
    unsigned int r = x.i + 0x7FFFu + ((x.i >> 16) & 1u);   // round-to-nearest-even
    return (unsigned short)(r >> 16);
}

// ---------- Kernel 0: segment starts. seg[n] = first pair index with node >= n. ----------
__global__ __launch_bounds__(256)
void seg_start_kernel(const int* __restrict__ pair_node, int* __restrict__ seg) {
    const int p = blockIdx.x * 256 + threadIdx.x;
    if (p >= N_PAIRS) return;
    const int cur  = pair_node[p];
    const int prev = (p == 0) ? -1 : pair_node[p - 1];
    for (int n = prev + 1; n <= cur; ++n) seg[n] = p;
    if (p == N_PAIRS - 1)
        for (int n = cur + 1; n <= N_NODES; ++n) seg[n] = N_PAIRS;
}

// ---------- Kernel A: FW = F @ W, stored bf16. W staged fully in LDS. ----------
__global__ __launch_bounds__(256)
void fw_gemm_kernel(const float* __restrict__ F, const float* __restrict__ W,
                    unsigned short* __restrict__ FWb)
{
    __shared__ float sW[DIM * DIM];   // 64 KiB
    __shared__ float sF[2][DIM];

    for (int idx = threadIdx.x; idx < DIM * DIM; idx += 256)
        sW[idx] = W[idx];

    const int sub = threadIdx.x >> 7;
    const int d   = threadIdx.x & 127;
    const int row0 = blockIdx.x * 32;

    for (int rp = 0; rp < 16; ++rp) {
        const int m = row0 + rp * 2 + sub;
        __syncthreads();
        sF[sub][d] = (m < N_NODES) ? F[(size_t)m * DIM + d] : 0.0f;
        __syncthreads();
        float o = 0.0f;
        #pragma unroll 16
        for (int k = 0; k < DIM; ++k)
            o += sF[sub][k] * sW[k * DIM + d];
        if (m < N_NODES) FWb[(size_t)m * DIM + d] = f2bf(o);
    }
}

// ---------- Fused: per-node pair weights (burst, row-local) + segment-sum + bias ----------
// 512 threads = 8 waves = 16 half-wave pair-lanes x 32 lanes (4 dims each, ushort4).
__global__ __launch_bounds__(512, 4)
void fused_seg_kernel(const float* __restrict__ dist,
                      const ushort4* __restrict__ FWb4,   // [N_NODES][32]
                      const int* __restrict__ seg,
                      const int* __restrict__ pair_i,
                      const int* __restrict__ pair_j,
                      const float* __restrict__ pair_cos,
                      const float* __restrict__ b,
                      float* __restrict__ out)
{
    const int n   = blockIdx.x;
    const int tid = threadIdx.x;
    const int hl  = tid >> 5;   // half-wave pair-lane 0..15
    const int ln  = tid & 31;   // lane: dims 4*ln .. 4*ln+3

    __shared__ float4 sPair[WCHUNK];      // (i_bits, j_bits, w, pad) — 4 KiB
    __shared__ float  sAcc[16][DIM];      // 8 KiB

    const int lo = seg[n];
    const int hi = seg[n + 1];
    const size_t drow = (size_t)n * N_NODES;

    float a0 = 0.f, a1 = 0.f, a2 = 0.f, a3 = 0.f;

    for (int base = lo; base < hi; base += WCHUNK) {
        const int m = min(WCHUNK, hi - base);

        // ---- phase 1: burst pair weights into LDS (dist row hot in L1/L2) ----
        for (int t = tid; t < m; t += 512) {
            const int i = pair_i[base + t];
            const int j = pair_j[base + t];
            const float w = pair_cos[base + t] * dist[drow + i] * dist[drow + j];
            float4 e;
            e.x = __int_as_float(i); e.y = __int_as_float(j); e.z = w; e.w = 0.f;
            sPair[t] = e;
        }
        __syncthreads();

        // ---- phase 2: accumulate w*(FW[i]+FW[j]); unroll 4 => 8 gathers in flight ----
        int q = hl;
        for (; q + 48 < m; q += 64) {
            const float4 e0 = sPair[q];
            const float4 e1 = sPair[q + 16];
            const float4 e2 = sPair[q + 32];
            const float4 e3 = sPair[q + 48];
            const ushort4 fi0 = FWb4[(size_t)__float_as_int(e0.x) * 32 + ln];
            const ushort4 fj0 = FWb4[(size_t)__float_as_int(e0.y) * 32 + ln];
            const ushort4 fi1 = FWb4[(size_t)__float_as_int(e1.x) * 32 + ln];
            const ushort4 fj1 = FWb4[(size_t)__float_as_int(e1.y) * 32 + ln];
            const ushort4 fi2 = FWb4[(size_t)__float_as_int(e2.x) * 32 + ln];
            const ushort4 fj2 = FWb4[(size_t)__float_as_int(e2.y) * 32 + ln];
            const ushort4 fi3 = FWb4[(size_t)__float_as_int(e3.x) * 32 + ln];
            const ushort4 fj3 = FWb4[(size_t)__float_as_int(e3.y) * 32 + ln];
            a0 += e0.z * (bf2f(fi0.x) + bf2f(fj0.x));
            a1 += e0.z * (bf2f(fi0.y) + bf2f(fj0.y));
            a2 += e0.z * (bf2f(fi0.z) + bf2f(fj0.z));
            a3 += e0.z * (bf2f(fi0.w) + bf2f(fj0.w));
            a0 += e1.z * (bf2f(fi1.x) + bf2f(fj1.x));
            a1 += e1.z * (bf2f(fi1.y) + bf2f(fj1.y));
            a2 += e1.z * (bf2f(fi1.z) + bf2f(fj1.z));
            a3 += e1.z * (bf2f(fi1.w) + bf2f(fj1.w));
            a0 += e2.z * (bf2f(fi2.x) + bf2f(fj2.x));
            a1 += e2.z * (bf2f(fi2.y) + bf2f(fj2.y));
            a2 += e2.z * (bf2f(fi2.z) + bf2f(fj2.z));
            a3 += e2.z * (bf2f(fi2.w) + bf2f(fj2.w));
            a0 += e3.z * (bf2f(fi3.x) + bf2f(fj3.x));
            a1 += e3.z * (bf2f(fi3.y) + bf2f(fj3.y));
            a2 += e3.z * (bf2f(fi3.z) + bf2f(fj3.z));
            a3 += e3.z * (bf2f(fi3.w) + bf2f(fj3.w));
        }
        for (; q < m; q += 16) {
            const float4 e = sPair[q];
            const ushort4 fi = FWb4[(size_t)__float_as_int(e.x) * 32 + ln];
            const ushort4 fj = FWb4[(size_t)__float_as_int(e.y) * 32 + ln];
            a0 += e.z * (bf2f(fi.x) + bf2f(fj.x));
            a1 += e.z * (bf2f(fi.y) + bf2f(fj.y));
            a2 += e.z * (bf2f(fi.z) + bf2f(fj.z));
            a3 += e.z * (bf2f(fi.w) + bf2f(fj.w));
        }
        __syncthreads();   // LDS reused next chunk (rare)
    }

    // ---- reduce 16 partials, add bias, write ----
    float4 av; av.x = a0; av.y = a1; av.z = a2; av.w = a3;
    *(float4*)&sAcc[hl][ln * 4] = av;
    __syncthreads();

    if (tid < DIM) {
        float t = b[tid];
        #pragma unroll
        for (int q2 = 0; q2 < 16; ++q2) t += sAcc[q2][tid];
        out[(size_t)n * DIM + tid] = t;
    }
}

extern "C" void kernel_launch(void* const* d_in, const int* in_sizes, int n_in,
                              void* d_out, int out_size, void* d_ws, size_t ws_size,
                              hipStream_t stream) {
    const float* features  = (const float*)d_in[0];
    const float* dist      = (const float*)d_in[1];
    const int*   pair_node = (const int*)  d_in[2];
    const int*   pair_i    = (const int*)  d_in[3];
    const int*   pair_j    = (const int*)  d_in[4];
    const float* pair_cos  = (const float*)d_in[5];
    const float* W         = (const float*)d_in[6];
    const float* b         = (const float*)d_in[7];
    float* out = (float*)d_out;

    // workspace: seg int[N_NODES+1] (40 KB, 256B-aligned pad) then FWb bf16 (2.56 MB)
    int* seg = (int*)d_ws;
    unsigned short* FWb = (unsigned short*)((char*)d_ws + 10240 * sizeof(int));

    seg_start_kernel<<<(N_PAIRS + 255) / 256, 256, 0, stream>>>(pair_node, seg);
    fw_gemm_kernel<<<(N_NODES + 31) / 32, 256, 0, stream>>>(features, W, FWb);
    fused_seg_kernel<<<N_NODES, 512, 0, stream>>>(
        dist, (const ushort4*)FWb, seg, pair_i, pair_j, pair_cos, b, out);
}

// Round 5
// 103.653 us; speedup vs baseline: 2.0283x; 1.0795x over previous
//
#include <hip/hip_runtime.h>

#define N_NODES 10000
#define N_PAIRS 1200000
#define DIM 128

__device__ inline float bf2f(unsigned short u) {
    return __uint_as_float(((unsigned int)u) << 16);
}
__device__ inline unsigned short f2bf(float f) {
    unsigned int i = __float_as_uint(f);
    unsigned int r = i + 0x7FFFu + ((i >> 16) & 1u);   // round-to-nearest-even
    return (unsigned short)(r >> 16);
}
__device__ inline float rl_f(float v, int q) {
    return __uint_as_float(__builtin_amdgcn_readlane(__float_as_uint(v), q));
}

// ---------- Kernel 0: segment starts. seg[n] = first pair index with node >= n. ----------
__global__ __launch_bounds__(256)
void seg_start_kernel(const int* __restrict__ pair_node, int* __restrict__ seg) {
    const int p = blockIdx.x * 256 + threadIdx.x;
    if (p >= N_PAIRS) return;
    const int cur  = pair_node[p];
    const int prev = (p == 0) ? -1 : pair_node[p - 1];
    for (int n = prev + 1; n <= cur; ++n) seg[n] = p;
    if (p == N_PAIRS - 1)
        for (int n = cur + 1; n <= N_NODES; ++n) seg[n] = N_PAIRS;
}

// ---------- Kernel A: FW = F @ W (bf16 out). Wave-per-4-rows, register-only. ----------
__global__ __launch_bounds__(256, 4)
void fw_gemm_kernel(const float* __restrict__ F, const float* __restrict__ W,
                    ushort2* __restrict__ FWb2)
{
    const int wid  = threadIdx.x >> 6;
    const int lane = threadIdx.x & 63;
    const int m0   = (blockIdx.x * 4 + wid) * 4;       // 4 rows per wave
    if (m0 >= N_NODES) return;

    const float2* F2 = (const float2*)F;
    const float2* W2 = (const float2*)W;

    // lane holds k = {2*lane, 2*lane+1} of each F row
    const float2 f0 = F2[(size_t)(m0 + 0) * 64 + lane];
    const float2 f1 = F2[(size_t)(m0 + 1) * 64 + lane];
    const float2 f2 = F2[(size_t)(m0 + 2) * 64 + lane];
    const float2 f3 = F2[(size_t)(m0 + 3) * 64 + lane];

    float2 a0 = {0.f, 0.f}, a1 = {0.f, 0.f}, a2 = {0.f, 0.f}, a3 = {0.f, 0.f};

    #pragma unroll 4
    for (int kk = 0; kk < 64; ++kk) {
        // W rows k=2kk and k=2kk+1, lane covers dims {2*lane, 2*lane+1}
        const float2 wa = W2[(size_t)(2 * kk + 0) * 64 + lane];
        const float2 wb = W2[(size_t)(2 * kk + 1) * 64 + lane];
        const float s0x = rl_f(f0.x, kk), s0y = rl_f(f0.y, kk);
        const float s1x = rl_f(f1.x, kk), s1y = rl_f(f1.y, kk);
        const float s2x = rl_f(f2.x, kk), s2y = rl_f(f2.y, kk);
        const float s3x = rl_f(f3.x, kk), s3y = rl_f(f3.y, kk);
        a0.x += s0x * wa.x + s0y * wb.x;  a0.y += s0x * wa.y + s0y * wb.y;
        a1.x += s1x * wa.x + s1y * wb.x;  a1.y += s1x * wa.y + s1y * wb.y;
        a2.x += s2x * wa.x + s2y * wb.x;  a2.y += s2x * wa.y + s2y * wb.y;
        a3.x += s3x * wa.x + s3y * wb.x;  a3.y += s3x * wa.y + s3y * wb.y;
    }

    ushort2 o;
    o.x = f2bf(a0.x); o.y = f2bf(a0.y); FWb2[(size_t)(m0 + 0) * 64 + lane] = o;
    o.x = f2bf(a1.x); o.y = f2bf(a1.y); FWb2[(size_t)(m0 + 1) * 64 + lane] = o;
    o.x = f2bf(a2.x); o.y = f2bf(a2.y); FWb2[(size_t)(m0 + 2) * 64 + lane] = o;
    o.x = f2bf(a3.x); o.y = f2bf(a3.y); FWb2[(size_t)(m0 + 3) * 64 + lane] = o;
}

// ---------- Fused: wave-per-node, barrier-free, LDS-free ----------
// Phase A (per 64-pair chunk): lane l computes w for pair base+l (2 dist gathers,
// row-local burst). Phase B: loop q over chunk; readlane-broadcast (i,j,w) -> SGPRs;
// each lane accumulates dims {2*lane, 2*lane+1} from ushort2 FW rows (L2-resident).
__global__ __launch_bounds__(256, 8)
void fused_seg_kernel(const float* __restrict__ dist,
                      const ushort2* __restrict__ FW2,   // [N_NODES][64]
                      const int* __restrict__ seg,
                      const int* __restrict__ pair_i,
                      const int* __restrict__ pair_j,
                      const float* __restrict__ pair_cos,
                      const float* __restrict__ b,
                      float* __restrict__ out)
{
    const int wid  = threadIdx.x >> 6;
    const int lane = threadIdx.x & 63;
    const int n    = blockIdx.x * 4 + wid;     // grid = 2500 x 4 waves = 10000
    const int lo = seg[n];
    const int hi = seg[n + 1];
    const size_t drow = (size_t)n * N_NODES;

    float a0 = 0.f, a1 = 0.f;

    for (int base = lo; base < hi; base += 64) {
        // ---- phase A: this lane's pair weight ----
        const int p = base + lane;
        int il = 0, jl = 0; float wl = 0.f;
        if (p < hi) {
            il = pair_i[p];
            jl = pair_j[p];
            wl = pair_cos[p] * dist[drow + il] * dist[drow + jl];
        }

        // ---- phase B: broadcast each pair, gather FW rows, accumulate ----
        const int qmax = min(64, hi - base);
        if (qmax == 64) {
            #pragma unroll 8
            for (int q = 0; q < 64; ++q) {
                const int   iq = __builtin_amdgcn_readlane(il, q);
                const int   jq = __builtin_amdgcn_readlane(jl, q);
                const float wq = rl_f(wl, q);
                const ushort2 fi = FW2[(size_t)iq * 64 + lane];
                const ushort2 fj = FW2[(size_t)jq * 64 + lane];
                a0 += wq * (bf2f(fi.x) + bf2f(fj.x));
                a1 += wq * (bf2f(fi.y) + bf2f(fj.y));
            }
        } else {
            #pragma unroll 4
            for (int q = 0; q < qmax; ++q) {
                const int   iq = __builtin_amdgcn_readlane(il, q);
                const int   jq = __builtin_amdgcn_readlane(jl, q);
                const float wq = rl_f(wl, q);
                const ushort2 fi = FW2[(size_t)iq * 64 + lane];
                const ushort2 fj = FW2[(size_t)jq * 64 + lane];
                a0 += wq * (bf2f(fi.x) + bf2f(fj.x));
                a1 += wq * (bf2f(fi.y) + bf2f(fj.y));
            }
        }
    }

    const float2 bb = ((const float2*)b)[lane];
    float2 o; o.x = a0 + bb.x; o.y = a1 + bb.y;
    ((float2*)out)[(size_t)n * 64 + lane] = o;
}

extern "C" void kernel_launch(void* const* d_in, const int* in_sizes, int n_in,
                              void* d_out, int out_size, void* d_ws, size_t ws_size,
                              hipStream_t stream) {
    const float* features  = (const float*)d_in[0];
    const float* dist      = (const float*)d_in[1];
    const int*   pair_node = (const int*)  d_in[2];
    const int*   pair_i    = (const int*)  d_in[3];
    const int*   pair_j    = (const int*)  d_in[4];
    const float* pair_cos  = (const float*)d_in[5];
    const float* W         = (const float*)d_in[6];
    const float* b         = (const float*)d_in[7];
    float* out = (float*)d_out;

    // workspace: seg int[N_NODES+1] (padded to 40960B), then FWb bf16 (2.56 MB)
    int* seg = (int*)d_ws;
    ushort2* FWb2 = (ushort2*)((char*)d_ws + 10240 * sizeof(int));

    seg_start_kernel<<<(N_PAIRS + 255) / 256, 256, 0, stream>>>(pair_node, seg);
    fw_gemm_kernel<<<(N_NODES / 16 + 0), 256, 0, stream>>>(features, W, FWb2);  // 625 blocks
    fused_seg_kernel<<<N_NODES / 4, 256, 0, stream>>>(
        dist, FWb2, seg, pair_i, pair_j, pair_cos, b, out);
}